// Round 1
// baseline (289.110 us; speedup 1.0000x reference)
//
#include <hip/hip_runtime.h>
#include <hip/hip_bf16.h>
#include <math.h>

// Problem constants
#define BB 2
#define LL 512
#define HH 768
#define EE 512
#define RR 32768
#define H2 384
// M = B*E = 1024 entity rows, repr dim 2H = 1536

// ---------------------------------------------------------------------------
// Kernel A: build X[m, 0:1536] = concat(hidden[b, ent_start[b,e]], emb[ent_label[b,e]])
// m = b*512 + e. 1024 blocks x 192 threads, each thread copies 2 float4s.
// ---------------------------------------------------------------------------
__global__ __launch_bounds__(192) void build_x(
    const float* __restrict__ hidden, const int* __restrict__ ent_start,
    const int* __restrict__ ent_label, const float* __restrict__ emb,
    float* __restrict__ X)
{
    const int m = blockIdx.x;            // 0..1023
    const int b = m >> 9;                // /512
    const int idx = ent_start[m];        // token position in [0,L)
    const int lab = ent_label[m];        // in [0,3)
    const float4* hsrc = (const float4*)(hidden + ((size_t)(b * LL + idx)) * HH);
    const float4* esrc = (const float4*)(emb + (size_t)lab * HH);
    float4* dst = (float4*)(X + (size_t)m * (2 * HH));
    const int t = threadIdx.x;           // 0..191
    dst[t]        = hsrc[t];             // first 768 floats = 192 float4
    dst[t + 192]  = esrc[t];             // next  768 floats
}

// ---------------------------------------------------------------------------
// Generic fp32 tiled GEMM, output split into two "halves" along N (head/tail
// or o=0/o=1), each half with its own B matrix, bias, and A k-offset.
// C[m, n] = act( sum_k A[m, aoff_h + k] * Bh[k, n%Nh] + bias_h[n%Nh] )
// 64x64 tile, 256 threads, 4x4 microtile, BK=16. M=1024 fixed multiple of 64.
// ---------------------------------------------------------------------------
template<bool RELU>
__global__ __launch_bounds__(256) void gemm2half(
    const float* __restrict__ A, int lda, int aoff1,
    const float* __restrict__ B0, const float* __restrict__ B1, int Nh,
    const float* __restrict__ bias0, const float* __restrict__ bias1,
    int K, float* __restrict__ C, int ldc)
{
    __shared__ float As[16][68];   // [k][m], padded
    __shared__ float Bs[16][64];   // [k][n]

    const int tid = threadIdx.x;
    const int n0 = blockIdx.x * 64;
    const int m0 = blockIdx.y * 64;
    const int half = (n0 >= Nh) ? 1 : 0;
    const float* Bh = half ? B1 : B0;
    const float* biash = half ? bias1 : bias0;
    const int nc0 = n0 - half * Nh;
    const int aoff = half ? aoff1 : 0;

    const int la_m = tid >> 2;          // 0..63
    const int la_k = (tid & 3) * 4;     // 0,4,8,12
    const int lb_k = tid >> 4;          // 0..15
    const int lb_n = (tid & 15) * 4;    // 0..60
    const int tx = tid & 15;            // col group
    const int ty = tid >> 4;            // row group

    float acc[4][4] = {};

    for (int k0 = 0; k0 < K; k0 += 16) {
        const float4 av = *(const float4*)(A + (size_t)(m0 + la_m) * lda + aoff + k0 + la_k);
        const float4 bv = *(const float4*)(Bh + (size_t)(k0 + lb_k) * Nh + nc0 + lb_n);
        __syncthreads();
        As[la_k + 0][la_m] = av.x;
        As[la_k + 1][la_m] = av.y;
        As[la_k + 2][la_m] = av.z;
        As[la_k + 3][la_m] = av.w;
        *(float4*)&Bs[lb_k][lb_n] = bv;
        __syncthreads();
        #pragma unroll
        for (int kk = 0; kk < 16; ++kk) {
            const float4 a = *(const float4*)&As[kk][ty * 4];
            const float4 bvv = *(const float4*)&Bs[kk][tx * 4];
            const float a4[4] = {a.x, a.y, a.z, a.w};
            const float b4[4] = {bvv.x, bvv.y, bvv.z, bvv.w};
            #pragma unroll
            for (int i = 0; i < 4; ++i)
                #pragma unroll
                for (int j = 0; j < 4; ++j)
                    acc[i][j] += a4[i] * b4[j];
        }
    }

    #pragma unroll
    for (int i = 0; i < 4; ++i) {
        const int m = m0 + ty * 4 + i;
        float4 o;
        float v[4];
        #pragma unroll
        for (int j = 0; j < 4; ++j) {
            float x = acc[i][j];
            if (biash) x += biash[nc0 + tx * 4 + j];
            if (RELU) x = fmaxf(x, 0.f);
            v[j] = x;
        }
        o.x = v[0]; o.y = v[1]; o.z = v[2]; o.w = v[3];
        *(float4*)(C + (size_t)m * ldc + n0 + tx * 4) = o;
    }
}

// ---------------------------------------------------------------------------
// Kernel D2: hlin[m,o] = dot(heads[m], lin_W[0:384, o])
//            tlin[m,o] = dot(tails[m], lin_W[384:768, o])
// One wave per m; 256 blocks x 256 threads (4 waves).
// HT layout: HT[m*768 + 0:384] = heads, HT[m*768 + 384:768] = tails.
// ---------------------------------------------------------------------------
__global__ __launch_bounds__(256) void lin_proj(
    const float* __restrict__ HT, const float* __restrict__ linW,
    float* __restrict__ hlin, float* __restrict__ tlin)
{
    const int tid = threadIdx.x;
    const int lane = tid & 63;
    const int wave = tid >> 6;
    const int m = blockIdx.x * 4 + wave;   // 0..1023
    const float* hr = HT + (size_t)m * 768;
    const float* tr = hr + 384;
    float hl0 = 0.f, hl1 = 0.f, tl0 = 0.f, tl1 = 0.f;
    #pragma unroll
    for (int t = 0; t < 6; ++t) {
        const int c = lane + 64 * t;
        const float hv = hr[c];
        const float tv = tr[c];
        const float2 wh = *(const float2*)(linW + 2 * c);
        const float2 wt = *(const float2*)(linW + 2 * (384 + c));
        hl0 += hv * wh.x; hl1 += hv * wh.y;
        tl0 += tv * wt.x; tl1 += tv * wt.y;
    }
    #pragma unroll
    for (int o = 32; o >= 1; o >>= 1) {
        hl0 += __shfl_xor(hl0, o, 64);
        hl1 += __shfl_xor(hl1, o, 64);
        tl0 += __shfl_xor(tl0, o, 64);
        tl1 += __shfl_xor(tl1, o, 64);
    }
    if (lane == 0) {
        hlin[2 * m]     = hl0;
        hlin[2 * m + 1] = hl1;
        tlin[2 * m]     = tl0;
        tlin[2 * m + 1] = tl1;
    }
}

// ---------------------------------------------------------------------------
// Kernel E: per-relation logits + CE partial sums. One wave per relation
// (grid-strided: 512 blocks x 4 waves x 32 relations = 65536).
// logit[o] = dot(hW[mh, o, :], tails[mt]) + hlin[mh,o] + tlin[mt,o] + lin_b[o]
// ---------------------------------------------------------------------------
__global__ __launch_bounds__(256) void rel_kernel(
    const float* __restrict__ HT, const float* __restrict__ hW,
    const float* __restrict__ hlin, const float* __restrict__ tlin,
    const float* __restrict__ lin_b,
    const int* __restrict__ rel_head, const int* __restrict__ rel_tail,
    const int* __restrict__ rel_label,
    float* __restrict__ out, float* __restrict__ bsum)
{
    const int tid = threadIdx.x;
    const int lane = tid & 63;
    const int wave = tid >> 6;
    const int gw = blockIdx.x * 4 + wave;       // 0..2047
    const float b0 = lin_b[0], b1 = lin_b[1];
    float ce_acc = 0.f;

    for (int t = 0; t < 32; ++t) {
        const int i = gw * 32 + t;              // relation 0..65535
        const int b = i >> 15;
        const int h = rel_head[i];
        const int tl = rel_tail[i];
        const int lab = rel_label[i];
        const int mh = (b << 9) + h;
        const int mt = (b << 9) + tl;
        const float* trow = HT + (size_t)mt * 768 + 384;   // tails
        const float* h0   = hW + (size_t)mh * 768;         // hW o=0 then o=1
        float s0 = 0.f, s1 = 0.f;
        #pragma unroll
        for (int j = 0; j < 6; ++j) {
            const int c = lane + 64 * j;
            const float tv = trow[c];
            s0 += h0[c] * tv;
            s1 += h0[384 + c] * tv;
        }
        #pragma unroll
        for (int o = 32; o >= 1; o >>= 1) {
            s0 += __shfl_xor(s0, o, 64);
            s1 += __shfl_xor(s1, o, 64);
        }
        const float z0 = s0 + hlin[2 * mh]     + tlin[2 * mt]     + b0;
        const float z1 = s1 + hlin[2 * mh + 1] + tlin[2 * mt + 1] + b1;
        if (lane < 2) out[1 + 2 * (size_t)i + lane] = lane ? z1 : z0;
        const float mx = fmaxf(z0, z1);
        const float lse = mx + logf(expf(z0 - mx) + expf(z1 - mx));
        ce_acc += lse - (lab ? z1 : z0);
    }

    __shared__ float wsum[4];
    if (lane == 0) wsum[wave] = ce_acc;
    __syncthreads();
    if (tid == 0) bsum[blockIdx.x] = wsum[0] + wsum[1] + wsum[2] + wsum[3];
}

// ---------------------------------------------------------------------------
// Kernel F: reduce 512 block sums -> loss = total / R   (sum over b of mean_r)
// ---------------------------------------------------------------------------
__global__ __launch_bounds__(512) void finalize(
    const float* __restrict__ bsum, float* __restrict__ out)
{
    const int tid = threadIdx.x;
    float v = bsum[tid];
    #pragma unroll
    for (int o = 32; o >= 1; o >>= 1) v += __shfl_xor(v, o, 64);
    __shared__ float s[8];
    if ((tid & 63) == 0) s[tid >> 6] = v;
    __syncthreads();
    if (tid == 0) {
        float t = 0.f;
        #pragma unroll
        for (int i = 0; i < 8; ++i) t += s[i];
        out[0] = t * (1.0f / (float)RR);
    }
}

// ---------------------------------------------------------------------------
extern "C" void kernel_launch(void* const* d_in, const int* in_sizes, int n_in,
                              void* d_out, int out_size, void* d_ws, size_t ws_size,
                              hipStream_t stream) {
    const float* hidden    = (const float*)d_in[0];
    const int*   ent_start = (const int*)d_in[1];
    const int*   ent_label = (const int*)d_in[2];
    const int*   rel_head  = (const int*)d_in[3];
    const int*   rel_tail  = (const int*)d_in[4];
    const int*   rel_label = (const int*)d_in[5];
    const float* emb       = (const float*)d_in[6];
    const float* head_W1   = (const float*)d_in[7];
    const float* head_b1   = (const float*)d_in[8];
    const float* head_W2   = (const float*)d_in[9];
    const float* head_b2   = (const float*)d_in[10];
    const float* tail_W1   = (const float*)d_in[11];
    const float* tail_b1   = (const float*)d_in[12];
    const float* tail_W2   = (const float*)d_in[13];
    const float* tail_b2   = (const float*)d_in[14];
    const float* bil_W     = (const float*)d_in[15];
    const float* lin_W     = (const float*)d_in[16];
    const float* lin_b     = (const float*)d_in[17];
    float* out = (float*)d_out;

    // Workspace layout (floats)
    float* ws = (float*)d_ws;
    float* X    = ws;                       // 1024 x 1536
    float* Y1   = X    + 1024 * 1536;       // 1024 x 1536 (head hid | tail hid)
    float* HT   = Y1   + 1024 * 1536;       // 1024 x 768  (heads | tails)
    float* hW   = HT   + 1024 * 768;        // 1024 x 768  (o=0 | o=1)
    float* hlin = hW   + 1024 * 768;        // 1024 x 2
    float* tlin = hlin + 2048;              // 1024 x 2
    float* bsum = tlin + 2048;              // 512

    // A: gather entity representations
    build_x<<<1024, 192, 0, stream>>>(hidden, ent_start, ent_label, emb, X);

    // B: layer1 for head+tail MLPs (N = 768+768, K = 1536), relu
    gemm2half<true><<<dim3(24, 16), 256, 0, stream>>>(
        X, 1536, 0, head_W1, tail_W1, 768, head_b1, tail_b1, 1536, Y1, 1536);

    // C: layer2 (N = 384+384, K = 768, A k-offset 768 for tail half), relu
    gemm2half<true><<<dim3(12, 16), 256, 0, stream>>>(
        Y1, 1536, 768, head_W2, tail_W2, 384, head_b2, tail_b2, 768, HT, 768);

    // D: hW[m, o*384 + e] = heads[m] @ bil_W[o]   (N = 384+384, K = 384)
    gemm2half<false><<<dim3(12, 16), 256, 0, stream>>>(
        HT, 768, 0, bil_W, bil_W + 384 * 384, 384, nullptr, nullptr, 384, hW, 768);

    // D2: linear projections to scalars
    lin_proj<<<256, 256, 0, stream>>>(HT, lin_W, hlin, tlin);

    // E: per-relation logits + CE partials
    rel_kernel<<<512, 256, 0, stream>>>(HT, hW, hlin, tlin, lin_b,
                                        rel_head, rel_tail, rel_label, out, bsum);

    // F: loss reduction
    finalize<<<1, 512, 0, stream>>>(bsum, out);
}

// Round 2
// 265.671 us; speedup vs baseline: 1.0882x; 1.0882x over previous
//
#include <hip/hip_runtime.h>
#include <hip/hip_bf16.h>
#include <math.h>

// Problem constants
#define BB 2
#define LL 512
#define HH 768
#define EE 512
#define RR 32768
#define H2 384
#define MM 1024   // B*E entity rows

// ---------------------------------------------------------------------------
// Kernel A: X[m, 0:1536] = concat(hidden[b, ent_start[b,e]], emb[ent_label[b,e]])
// ---------------------------------------------------------------------------
__global__ __launch_bounds__(192) void build_x(
    const float* __restrict__ hidden, const int* __restrict__ ent_start,
    const int* __restrict__ ent_label, const float* __restrict__ emb,
    float* __restrict__ X)
{
    const int m = blockIdx.x;            // 0..1023
    const int b = m >> 9;
    const int idx = ent_start[m];
    const int lab = ent_label[m];
    const float4* hsrc = (const float4*)(hidden + ((size_t)(b * LL + idx)) * HH);
    const float4* esrc = (const float4*)(emb + (size_t)lab * HH);
    float4* dst = (float4*)(X + (size_t)m * (2 * HH));
    const int t = threadIdx.x;           // 0..191
    dst[t]       = hsrc[t];
    dst[t + 192] = esrc[t];
}

// ---------------------------------------------------------------------------
// Split-K fp32 GEMM, 128x128 tile, 256 threads, 8x8 microtile, BK=16.
// N split into two halves (different B matrix / A k-offset per half).
// blockIdx.z = k-chunk; partial written to Cp + z*M*ldc (no epilogue).
// M fixed = 1024.
// ---------------------------------------------------------------------------
__global__ __launch_bounds__(256) void gemm_sk(
    const float* __restrict__ A, int lda, int aoff1,
    const float* __restrict__ B0, const float* __restrict__ B1, int Nh,
    int kchunk, float* __restrict__ Cp, int ldc)
{
    __shared__ float As[16][132];   // [k][m], padded
    __shared__ float Bs[16][128];   // [k][n]

    const int tid = threadIdx.x;
    const int n0 = blockIdx.x * 128;
    const int m0 = blockIdx.y * 128;
    const int kz = blockIdx.z;
    const int half = (n0 >= Nh) ? 1 : 0;
    const float* Bh = half ? B1 : B0;
    const int nc0 = n0 - (half ? Nh : 0);
    const int aoff = half ? aoff1 : 0;
    const int kbeg = kz * kchunk;

    // staging: A 128x16 (2 float4/thread), B 16x128 (2 float4/thread)
    const int am = tid >> 2;            // 0..63
    const int ak = (tid & 3) * 4;       // 0,4,8,12
    const int bk = tid >> 4;            // 0..15
    const int bn = (tid & 15) * 8;      // 0..120

    const float* Aptr = A + (size_t)(m0 + am) * lda + aoff + kbeg + ak;
    const float* Bptr = Bh + (size_t)(kbeg + bk) * Nh + nc0 + bn;

    const int tx = tid & 15;            // n group
    const int ty = tid >> 4;            // m group

    float acc[8][8] = {};

    for (int kt = 0; kt < kchunk; kt += 16) {
        const float4 a0 = *(const float4*)(Aptr);
        const float4 a1 = *(const float4*)(Aptr + (size_t)64 * lda);
        const float4 b0 = *(const float4*)(Bptr);
        const float4 b1 = *(const float4*)(Bptr + 4);
        __syncthreads();
        As[ak + 0][am]      = a0.x;
        As[ak + 1][am]      = a0.y;
        As[ak + 2][am]      = a0.z;
        As[ak + 3][am]      = a0.w;
        As[ak + 0][am + 64] = a1.x;
        As[ak + 1][am + 64] = a1.y;
        As[ak + 2][am + 64] = a1.z;
        As[ak + 3][am + 64] = a1.w;
        *(float4*)&Bs[bk][bn]     = b0;
        *(float4*)&Bs[bk][bn + 4] = b1;
        __syncthreads();
        #pragma unroll
        for (int kk = 0; kk < 16; ++kk) {
            const float4 A0 = *(const float4*)&As[kk][ty * 8];
            const float4 A1 = *(const float4*)&As[kk][ty * 8 + 4];
            const float4 Bv0 = *(const float4*)&Bs[kk][tx * 8];
            const float4 Bv1 = *(const float4*)&Bs[kk][tx * 8 + 4];
            const float av[8] = {A0.x, A0.y, A0.z, A0.w, A1.x, A1.y, A1.z, A1.w};
            const float bv[8] = {Bv0.x, Bv0.y, Bv0.z, Bv0.w, Bv1.x, Bv1.y, Bv1.z, Bv1.w};
            #pragma unroll
            for (int i = 0; i < 8; ++i)
                #pragma unroll
                for (int j = 0; j < 8; ++j)
                    acc[i][j] = fmaf(av[i], bv[j], acc[i][j]);
        }
        Aptr += 16;
        Bptr += (size_t)16 * Nh;
    }

    float* Co = Cp + (size_t)kz * MM * ldc + (size_t)(m0 + ty * 8) * ldc + n0 + tx * 8;
    #pragma unroll
    for (int i = 0; i < 8; ++i) {
        float4 o0 = {acc[i][0], acc[i][1], acc[i][2], acc[i][3]};
        float4 o1 = {acc[i][4], acc[i][5], acc[i][6], acc[i][7]};
        *(float4*)(Co + (size_t)i * ldc)     = o0;
        *(float4*)(Co + (size_t)i * ldc + 4) = o1;
    }
}

// ---------------------------------------------------------------------------
// Combine split-K partials + bias + relu.
// ---------------------------------------------------------------------------
template<bool RELU, bool BIAS>
__global__ __launch_bounds__(256) void combine_k(
    const float4* __restrict__ Cp, int S, int total4, int ldc4, int Nh,
    const float* __restrict__ bias0, const float* __restrict__ bias1,
    float4* __restrict__ C)
{
    const int idx = blockIdx.x * 256 + threadIdx.x;
    if (idx >= total4) return;
    float4 s = Cp[idx];
    for (int z = 1; z < S; ++z) {
        const float4 v = Cp[idx + (size_t)z * total4];
        s.x += v.x; s.y += v.y; s.z += v.z; s.w += v.w;
    }
    if (BIAS) {
        const int n = (idx % ldc4) * 4;
        const float* bp = (n < Nh) ? (bias0 + n) : (bias1 + n - Nh);
        s.x += bp[0]; s.y += bp[1]; s.z += bp[2]; s.w += bp[3];
    }
    if (RELU) {
        s.x = fmaxf(s.x, 0.f); s.y = fmaxf(s.y, 0.f);
        s.z = fmaxf(s.z, 0.f); s.w = fmaxf(s.w, 0.f);
    }
    C[idx] = s;
}

// ---------------------------------------------------------------------------
// hlin[m,o] = dot(heads[m], lin_W[0:384, o]); tlin likewise with lin_W[384:].
// ---------------------------------------------------------------------------
__global__ __launch_bounds__(256) void lin_proj(
    const float* __restrict__ HT, const float* __restrict__ linW,
    float* __restrict__ hlin, float* __restrict__ tlin)
{
    const int tid = threadIdx.x;
    const int lane = tid & 63;
    const int wave = tid >> 6;
    const int m = blockIdx.x * 4 + wave;
    const float* hr = HT + (size_t)m * 768;
    const float* tr = hr + 384;
    float hl0 = 0.f, hl1 = 0.f, tl0 = 0.f, tl1 = 0.f;
    #pragma unroll
    for (int t = 0; t < 6; ++t) {
        const int c = lane + 64 * t;
        const float hv = hr[c];
        const float tv = tr[c];
        const float2 wh = *(const float2*)(linW + 2 * c);
        const float2 wt = *(const float2*)(linW + 2 * (384 + c));
        hl0 += hv * wh.x; hl1 += hv * wh.y;
        tl0 += tv * wt.x; tl1 += tv * wt.y;
    }
    #pragma unroll
    for (int o = 32; o >= 1; o >>= 1) {
        hl0 += __shfl_xor(hl0, o, 64);
        hl1 += __shfl_xor(hl1, o, 64);
        tl0 += __shfl_xor(tl0, o, 64);
        tl1 += __shfl_xor(tl1, o, 64);
    }
    if (lane == 0) {
        hlin[2 * m]     = hl0;
        hlin[2 * m + 1] = hl1;
        tlin[2 * m]     = tl0;
        tlin[2 * m + 1] = tl1;
    }
}

// ---------------------------------------------------------------------------
// Per-relation logits + CE partials. One wave per relation (grid-strided).
// ---------------------------------------------------------------------------
__global__ __launch_bounds__(256) void rel_kernel(
    const float* __restrict__ HT, const float* __restrict__ hW,
    const float* __restrict__ hlin, const float* __restrict__ tlin,
    const float* __restrict__ lin_b,
    const int* __restrict__ rel_head, const int* __restrict__ rel_tail,
    const int* __restrict__ rel_label,
    float* __restrict__ out, float* __restrict__ bsum)
{
    const int tid = threadIdx.x;
    const int lane = tid & 63;
    const int wave = tid >> 6;
    const int gw = blockIdx.x * 4 + wave;       // 0..2047
    const float b0 = lin_b[0], b1 = lin_b[1];
    float ce_acc = 0.f;

    for (int t = 0; t < 32; ++t) {
        const int i = gw * 32 + t;
        const int b = i >> 15;
        const int h = rel_head[i];
        const int tl = rel_tail[i];
        const int lab = rel_label[i];
        const int mh = (b << 9) + h;
        const int mt = (b << 9) + tl;
        const float* trow = HT + (size_t)mt * 768 + 384;
        const float* h0   = hW + (size_t)mh * 768;
        float s0 = 0.f, s1 = 0.f;
        #pragma unroll
        for (int j = 0; j < 6; ++j) {
            const int c = lane + 64 * j;
            const float tv = trow[c];
            s0 += h0[c] * tv;
            s1 += h0[384 + c] * tv;
        }
        #pragma unroll
        for (int o = 32; o >= 1; o >>= 1) {
            s0 += __shfl_xor(s0, o, 64);
            s1 += __shfl_xor(s1, o, 64);
        }
        const float z0 = s0 + hlin[2 * mh]     + tlin[2 * mt]     + b0;
        const float z1 = s1 + hlin[2 * mh + 1] + tlin[2 * mt + 1] + b1;
        if (lane < 2) out[1 + 2 * (size_t)i + lane] = lane ? z1 : z0;
        const float mx = fmaxf(z0, z1);
        const float lse = mx + logf(expf(z0 - mx) + expf(z1 - mx));
        ce_acc += lse - (lab ? z1 : z0);
    }

    __shared__ float wsum[4];
    if (lane == 0) wsum[wave] = ce_acc;
    __syncthreads();
    if (tid == 0) bsum[blockIdx.x] = wsum[0] + wsum[1] + wsum[2] + wsum[3];
}

__global__ __launch_bounds__(512) void finalize(
    const float* __restrict__ bsum, float* __restrict__ out)
{
    const int tid = threadIdx.x;
    float v = bsum[tid];
    #pragma unroll
    for (int o = 32; o >= 1; o >>= 1) v += __shfl_xor(v, o, 64);
    __shared__ float s[8];
    if ((tid & 63) == 0) s[tid >> 6] = v;
    __syncthreads();
    if (tid == 0) {
        float t = 0.f;
        #pragma unroll
        for (int i = 0; i < 8; ++i) t += s[i];
        out[0] = t * (1.0f / (float)RR);
    }
}

// ---------------------------------------------------------------------------
extern "C" void kernel_launch(void* const* d_in, const int* in_sizes, int n_in,
                              void* d_out, int out_size, void* d_ws, size_t ws_size,
                              hipStream_t stream) {
    const float* hidden    = (const float*)d_in[0];
    const int*   ent_start = (const int*)d_in[1];
    const int*   ent_label = (const int*)d_in[2];
    const int*   rel_head  = (const int*)d_in[3];
    const int*   rel_tail  = (const int*)d_in[4];
    const int*   rel_label = (const int*)d_in[5];
    const float* emb       = (const float*)d_in[6];
    const float* head_W1   = (const float*)d_in[7];
    const float* head_b1   = (const float*)d_in[8];
    const float* head_W2   = (const float*)d_in[9];
    const float* head_b2   = (const float*)d_in[10];
    const float* tail_W1   = (const float*)d_in[11];
    const float* tail_b1   = (const float*)d_in[12];
    const float* tail_W2   = (const float*)d_in[13];
    const float* tail_b2   = (const float*)d_in[14];
    const float* bil_W     = (const float*)d_in[15];
    const float* lin_W     = (const float*)d_in[16];
    const float* lin_b     = (const float*)d_in[17];
    float* out = (float*)d_out;

    // Workspace layout (floats)
    float* ws = (float*)d_ws;
    float* X    = ws;                       // 1024 x 1536
    float* Y1   = X    + MM * 1536;         // 1024 x 1536
    float* HT   = Y1   + MM * 1536;         // 1024 x 768 (heads | tails)
    float* hW   = HT   + MM * 768;          // 1024 x 768 (o=0 | o=1)
    float* hlin = hW   + MM * 768;          // 1024 x 2
    float* tlin = hlin + 2048;              // 1024 x 2
    float* bsum = tlin + 2048;              // 512
    float* Cp   = bsum + 512;               // split-K partials (shared)

    // Choose split-K for GEMM1 by available workspace (deterministic).
    const size_t base_floats = (size_t)(Cp - ws);
    const size_t avail = ws_size / 4 - base_floats;
    int S1 = 2;
    if (avail >= (size_t)8 * MM * 1536) S1 = 8;
    else if (avail >= (size_t)4 * MM * 1536) S1 = 4;
    const int kchunk1 = 1536 / S1;

    // A: gather entity representations
    build_x<<<1024, 192, 0, stream>>>(hidden, ent_start, ent_label, emb, X);

    // B: layer1 (N = 768+768, K = 1536) split-K
    gemm_sk<<<dim3(12, 8, S1), 256, 0, stream>>>(
        X, 1536, 0, head_W1, tail_W1, 768, kchunk1, Cp, 1536);
    combine_k<true, true><<<1536, 256, 0, stream>>>(
        (const float4*)Cp, S1, MM * 1536 / 4, 1536 / 4, 768,
        head_b1, tail_b1, (float4*)Y1);

    // C: layer2 (N = 384+384, K = 768, tail half reads A cols 768+)
    gemm_sk<<<dim3(6, 8, 4), 256, 0, stream>>>(
        Y1, 1536, 768, head_W2, tail_W2, 384, 192, Cp, 768);
    combine_k<true, true><<<768, 256, 0, stream>>>(
        (const float4*)Cp, 4, MM * 768 / 4, 768 / 4, 384,
        head_b2, tail_b2, (float4*)HT);

    // D: hW = heads @ bil_W[o]  (N = 384+384, K = 384)
    gemm_sk<<<dim3(6, 8, 4), 256, 0, stream>>>(
        HT, 768, 0, bil_W, bil_W + 384 * 384, 384, 96, Cp, 768);
    combine_k<false, false><<<768, 256, 0, stream>>>(
        (const float4*)Cp, 4, MM * 768 / 4, 768 / 4, 384,
        nullptr, nullptr, (float4*)hW);

    // D2: linear projections
    lin_proj<<<256, 256, 0, stream>>>(HT, lin_W, hlin, tlin);

    // E: per-relation logits + CE partials
    rel_kernel<<<512, 256, 0, stream>>>(HT, hW, hlin, tlin, lin_b,
                                        rel_head, rel_tail, rel_label, out, bsum);

    // F: loss reduction
    finalize<<<1, 512, 0, stream>>>(bsum, out);
}

// Round 3
// 188.011 us; speedup vs baseline: 1.5377x; 1.4131x over previous
//
#include <hip/hip_runtime.h>
#include <math.h>

// Problem constants
#define BB 2
#define LL 512
#define HH 768
#define EE 512
#define RR 32768
#define H2 384
#define MM 1024   // B*E entity rows

typedef __attribute__((ext_vector_type(8))) short     bf16x8;  // MFMA A/B frag (4 VGPRs)
typedef __attribute__((ext_vector_type(4))) float     f32x4;   // MFMA C/D frag
typedef __attribute__((ext_vector_type(8))) unsigned short u16x8;

__device__ __forceinline__ unsigned short f2bf(float f) {
    unsigned int u = __float_as_uint(f);
    u = (u + 0x7FFFu + ((u >> 16) & 1u)) >> 16;   // round-to-nearest-even
    return (unsigned short)u;
}

// ---------------------------------------------------------------------------
// prep: blocks [0,3168) transpose+convert the 6 weight matrices [K][N] fp32
// -> [N][K] bf16; blocks [3168,4192) build X bf16 (concat(hidden@start, emb)).
// ---------------------------------------------------------------------------
__global__ __launch_bounds__(256) void prep(
    const float* __restrict__ hW1, const float* __restrict__ tW1,
    const float* __restrict__ hW2, const float* __restrict__ tW2,
    const float* __restrict__ bilW,
    unsigned short* __restrict__ W1ht, unsigned short* __restrict__ W1tt,
    unsigned short* __restrict__ W2ht, unsigned short* __restrict__ W2tt,
    unsigned short* __restrict__ bW0t, unsigned short* __restrict__ bW1t,
    const float* __restrict__ hidden, const int* __restrict__ ent_start,
    const int* __restrict__ ent_label, const float* __restrict__ emb,
    unsigned short* __restrict__ Xbf)
{
    __shared__ unsigned short T[32 * 40];
    const int bid = blockIdx.x;
    const int t = threadIdx.x;

    if (bid >= 3168) {
        // ---- build X[m] = concat(hidden[b, ent_start], emb[label]) as bf16
        const int m = bid - 3168;          // 0..1023
        if (t >= 192) return;
        const int b = m >> 9;
        const int idx = ent_start[m];
        const int lab = ent_label[m];
        float4 v0, v1;
        if (t < 96) {
            const float4* s = (const float4*)(hidden + (size_t)(b * LL + idx) * HH);
            v0 = s[2 * t]; v1 = s[2 * t + 1];
        } else {
            const float4* s = (const float4*)(emb + (size_t)lab * HH);
            v0 = s[2 * t - 192]; v1 = s[2 * t - 191];
        }
        u16x8 o;
        o[0] = f2bf(v0.x); o[1] = f2bf(v0.y); o[2] = f2bf(v0.z); o[3] = f2bf(v0.w);
        o[4] = f2bf(v1.x); o[5] = f2bf(v1.y); o[6] = f2bf(v1.z); o[7] = f2bf(v1.w);
        *(u16x8*)(Xbf + (size_t)m * 1536 + 8 * t) = o;
        return;
    }

    // ---- weight transpose
    const float* src; unsigned short* dst; int K, N, tile;
    if (bid < 1152)      { src = hW1;            dst = W1ht; K = 1536; N = 768; tile = bid; }
    else if (bid < 2304) { src = tW1;            dst = W1tt; K = 1536; N = 768; tile = bid - 1152; }
    else if (bid < 2592) { src = hW2;            dst = W2ht; K = 768;  N = 384; tile = bid - 2304; }
    else if (bid < 2880) { src = tW2;            dst = W2tt; K = 768;  N = 384; tile = bid - 2592; }
    else if (bid < 3024) { src = bilW;           dst = bW0t; K = 384;  N = 384; tile = bid - 2880; }
    else                 { src = bilW + 384*384; dst = bW1t; K = 384;  N = 384; tile = bid - 3024; }
    const int tn = N >> 5;
    const int n0 = (tile % tn) * 32;
    const int k0 = (tile / tn) * 32;

    const int r  = t >> 3;           // 0..31 (k within tile)
    const int c4 = (t & 7) * 4;      // 0..28 (n within tile)
    const float4 g = *(const float4*)(src + (size_t)(k0 + r) * N + n0 + c4);
    T[(c4 + 0) * 40 + r] = f2bf(g.x);
    T[(c4 + 1) * 40 + r] = f2bf(g.y);
    T[(c4 + 2) * 40 + r] = f2bf(g.z);
    T[(c4 + 3) * 40 + r] = f2bf(g.w);
    __syncthreads();
    const int n  = t >> 3;           // 0..31
    const int k4 = (t & 7) * 4;      // 0..28
    *(ushort4*)(dst + (size_t)(n0 + n) * K + k0 + k4) = *(ushort4*)&T[n * 40 + k4];
}

// ---------------------------------------------------------------------------
// bf16 MFMA GEMM. 64x64 tile, 256 threads (4 waves, 2x2), 16x16x32 MFMA.
// A: [M][lda] bf16 row-major (k-contiguous), per-half k-offset aoff.
// B: transposed [Nh][K] bf16 (two halves along N with separate matrices).
// C = act(A·B + bias): written fp32 (Cf) and/or bf16 (Cb), ldc = full N.
// LDS rows padded to 40 bf16 (80 B): staging writes + frag reads at bank floor.
// ---------------------------------------------------------------------------
template<bool RELU, bool BIAS, bool WF32, bool WBF16>
__global__ __launch_bounds__(256) void gemm_mfma(
    const unsigned short* __restrict__ A, int lda, int aoff1,
    const unsigned short* __restrict__ Bt0, const unsigned short* __restrict__ Bt1,
    int Nh, const float* __restrict__ bias0, const float* __restrict__ bias1,
    int K, float* __restrict__ Cf, unsigned short* __restrict__ Cb, int ldc)
{
    __shared__ unsigned short As[64 * 40];
    __shared__ unsigned short Bs[64 * 40];

    const int tid = threadIdx.x;
    const int n0 = blockIdx.x * 64;
    const int m0 = blockIdx.y * 64;
    const int hf = (n0 >= Nh) ? 1 : 0;
    const unsigned short* Bt = hf ? Bt1 : Bt0;
    const int nc0 = n0 - (hf ? Nh : 0);
    const int aoff = hf ? aoff1 : 0;

    // staging: thread t covers row sr (m for A, n for B), 8 bf16 at k-offset sk
    const int sr = tid >> 2;            // 0..63
    const int sk = (tid & 3) * 8;       // 0,8,16,24

    const unsigned short* Ap = A + (size_t)(m0 + sr) * lda + aoff + sk;
    const unsigned short* Bp = Bt + (size_t)(nc0 + sr) * K + sk;

    const int lane = tid & 63;
    const int wave = tid >> 6;
    const int wm = (wave & 1) * 32;
    const int wn = (wave >> 1) * 32;
    const int l15 = lane & 15;
    const int quad = lane >> 4;

    f32x4 acc00 = {}, acc01 = {}, acc10 = {}, acc11 = {};

    for (int k0 = 0; k0 < K; k0 += 32) {
        const u16x8 av = *(const u16x8*)(Ap + k0);
        const u16x8 bv = *(const u16x8*)(Bp + k0);
        __syncthreads();                 // previous iter's readers done
        *(u16x8*)&As[sr * 40 + sk] = av;
        *(u16x8*)&Bs[sr * 40 + sk] = bv;
        __syncthreads();
        const bf16x8 a0 = *(const bf16x8*)&As[(wm + l15) * 40 + quad * 8];
        const bf16x8 a1 = *(const bf16x8*)&As[(wm + 16 + l15) * 40 + quad * 8];
        const bf16x8 b0 = *(const bf16x8*)&Bs[(wn + l15) * 40 + quad * 8];
        const bf16x8 b1 = *(const bf16x8*)&Bs[(wn + 16 + l15) * 40 + quad * 8];
        acc00 = __builtin_amdgcn_mfma_f32_16x16x32_bf16(a0, b0, acc00, 0, 0, 0);
        acc01 = __builtin_amdgcn_mfma_f32_16x16x32_bf16(a0, b1, acc01, 0, 0, 0);
        acc10 = __builtin_amdgcn_mfma_f32_16x16x32_bf16(a1, b0, acc10, 0, 0, 0);
        acc11 = __builtin_amdgcn_mfma_f32_16x16x32_bf16(a1, b1, acc11, 0, 0, 0);
    }

    // epilogue: C/D layout col=lane&15, row=quad*4+reg
    float bias_v0 = 0.f, bias_v1 = 0.f;
    if (BIAS) {
        const float* bb = hf ? bias1 : bias0;
        bias_v0 = bb[nc0 + wn + l15];
        bias_v1 = bb[nc0 + wn + 16 + l15];
    }
    const f32x4 accs[2][2] = {{acc00, acc01}, {acc10, acc11}};
    #pragma unroll
    for (int mi = 0; mi < 2; ++mi) {
        #pragma unroll
        for (int ni = 0; ni < 2; ++ni) {
            const int col = n0 + wn + ni * 16 + l15;
            const float bv = ni ? bias_v1 : bias_v0;
            #pragma unroll
            for (int r = 0; r < 4; ++r) {
                const int row = m0 + wm + mi * 16 + quad * 4 + r;
                float v = accs[mi][ni][r];
                if (BIAS) v += bv;
                if (RELU) v = fmaxf(v, 0.f);
                if (WF32) Cf[(size_t)row * ldc + col] = v;
                if (WBF16) Cb[(size_t)row * ldc + col] = f2bf(v);
            }
        }
    }
}

// ---------------------------------------------------------------------------
// hlin[m,o] = dot(heads[m], lin_W[0:384, o]); tlin from lin_W[384:768].
// ---------------------------------------------------------------------------
__global__ __launch_bounds__(256) void lin_proj(
    const float* __restrict__ HT, const float* __restrict__ linW,
    float* __restrict__ hlin, float* __restrict__ tlin)
{
    const int tid = threadIdx.x;
    const int lane = tid & 63;
    const int wave = tid >> 6;
    const int m = blockIdx.x * 4 + wave;
    const float* hr = HT + (size_t)m * 768;
    const float* tr = hr + 384;
    float hl0 = 0.f, hl1 = 0.f, tl0 = 0.f, tl1 = 0.f;
    #pragma unroll
    for (int t = 0; t < 6; ++t) {
        const int c = lane + 64 * t;
        const float hv = hr[c];
        const float tv = tr[c];
        const float2 wh = *(const float2*)(linW + 2 * c);
        const float2 wt = *(const float2*)(linW + 2 * (384 + c));
        hl0 += hv * wh.x; hl1 += hv * wh.y;
        tl0 += tv * wt.x; tl1 += tv * wt.y;
    }
    #pragma unroll
    for (int o = 32; o >= 1; o >>= 1) {
        hl0 += __shfl_xor(hl0, o, 64);
        hl1 += __shfl_xor(hl1, o, 64);
        tl0 += __shfl_xor(tl0, o, 64);
        tl1 += __shfl_xor(tl1, o, 64);
    }
    if (lane == 0) {
        hlin[2 * m]     = hl0;
        hlin[2 * m + 1] = hl1;
        tlin[2 * m]     = tl0;
        tlin[2 * m + 1] = tl1;
    }
}

// ---------------------------------------------------------------------------
// Per-relation logits + CE partials. One wave per relation (grid-strided).
// ---------------------------------------------------------------------------
__global__ __launch_bounds__(256) void rel_kernel(
    const float* __restrict__ HT, const float* __restrict__ hW,
    const float* __restrict__ hlin, const float* __restrict__ tlin,
    const float* __restrict__ lin_b,
    const int* __restrict__ rel_head, const int* __restrict__ rel_tail,
    const int* __restrict__ rel_label,
    float* __restrict__ out, float* __restrict__ bsum)
{
    const int tid = threadIdx.x;
    const int lane = tid & 63;
    const int wave = tid >> 6;
    const int gw = blockIdx.x * 4 + wave;       // 0..2047
    const float b0 = lin_b[0], b1 = lin_b[1];
    float ce_acc = 0.f;

    for (int t = 0; t < 32; ++t) {
        const int i = gw * 32 + t;
        const int b = i >> 15;
        const int h = rel_head[i];
        const int tl = rel_tail[i];
        const int lab = rel_label[i];
        const int mh = (b << 9) + h;
        const int mt = (b << 9) + tl;
        const float* trow = HT + (size_t)mt * 768 + 384;
        const float* h0   = hW + (size_t)mh * 768;
        float s0 = 0.f, s1 = 0.f;
        #pragma unroll
        for (int j = 0; j < 6; ++j) {
            const int c = lane + 64 * j;
            const float tv = trow[c];
            s0 += h0[c] * tv;
            s1 += h0[384 + c] * tv;
        }
        #pragma unroll
        for (int o = 32; o >= 1; o >>= 1) {
            s0 += __shfl_xor(s0, o, 64);
            s1 += __shfl_xor(s1, o, 64);
        }
        const float z0 = s0 + hlin[2 * mh]     + tlin[2 * mt]     + b0;
        const float z1 = s1 + hlin[2 * mh + 1] + tlin[2 * mt + 1] + b1;
        if (lane < 2) out[1 + 2 * (size_t)i + lane] = lane ? z1 : z0;
        const float mx = fmaxf(z0, z1);
        const float lse = mx + logf(expf(z0 - mx) + expf(z1 - mx));
        ce_acc += lse - (lab ? z1 : z0);
    }

    __shared__ float wsum[4];
    if (lane == 0) wsum[wave] = ce_acc;
    __syncthreads();
    if (tid == 0) bsum[blockIdx.x] = wsum[0] + wsum[1] + wsum[2] + wsum[3];
}

__global__ __launch_bounds__(512) void finalize(
    const float* __restrict__ bsum, float* __restrict__ out)
{
    const int tid = threadIdx.x;
    float v = bsum[tid];
    #pragma unroll
    for (int o = 32; o >= 1; o >>= 1) v += __shfl_xor(v, o, 64);
    __shared__ float s[8];
    if ((tid & 63) == 0) s[tid >> 6] = v;
    __syncthreads();
    if (tid == 0) {
        float t = 0.f;
        #pragma unroll
        for (int i = 0; i < 8; ++i) t += s[i];
        out[0] = t * (1.0f / (float)RR);
    }
}

// ---------------------------------------------------------------------------
extern "C" void kernel_launch(void* const* d_in, const int* in_sizes, int n_in,
                              void* d_out, int out_size, void* d_ws, size_t ws_size,
                              hipStream_t stream) {
    const float* hidden    = (const float*)d_in[0];
    const int*   ent_start = (const int*)d_in[1];
    const int*   ent_label = (const int*)d_in[2];
    const int*   rel_head  = (const int*)d_in[3];
    const int*   rel_tail  = (const int*)d_in[4];
    const int*   rel_label = (const int*)d_in[5];
    const float* emb       = (const float*)d_in[6];
    const float* head_W1   = (const float*)d_in[7];
    const float* head_b1   = (const float*)d_in[8];
    const float* head_W2   = (const float*)d_in[9];
    const float* head_b2   = (const float*)d_in[10];
    const float* tail_W1   = (const float*)d_in[11];
    const float* tail_b1   = (const float*)d_in[12];
    const float* tail_W2   = (const float*)d_in[13];
    const float* tail_b2   = (const float*)d_in[14];
    const float* bil_W     = (const float*)d_in[15];
    const float* lin_W     = (const float*)d_in[16];
    const float* lin_b     = (const float*)d_in[17];
    float* out = (float*)d_out;

    // Workspace carve-up (256B-aligned chunks)
    char* w = (char*)d_ws;
    auto carve = [&](size_t bytes) {
        char* p = w; w += (bytes + 255) & ~(size_t)255; return p;
    };
    unsigned short* Xbf  = (unsigned short*)carve((size_t)MM * 1536 * 2);
    unsigned short* Y1bf = (unsigned short*)carve((size_t)MM * 1536 * 2);
    unsigned short* HTbf = (unsigned short*)carve((size_t)MM * 768 * 2);
    float*          HT   = (float*)carve((size_t)MM * 768 * 4);
    float*          hW   = (float*)carve((size_t)MM * 768 * 4);
    unsigned short* W1ht = (unsigned short*)carve((size_t)768 * 1536 * 2);
    unsigned short* W1tt = (unsigned short*)carve((size_t)768 * 1536 * 2);
    unsigned short* W2ht = (unsigned short*)carve((size_t)384 * 768 * 2);
    unsigned short* W2tt = (unsigned short*)carve((size_t)384 * 768 * 2);
    unsigned short* bW0t = (unsigned short*)carve((size_t)384 * 384 * 2);
    unsigned short* bW1t = (unsigned short*)carve((size_t)384 * 384 * 2);
    float*          hlin = (float*)carve(2048 * 4);
    float*          tlin = (float*)carve(2048 * 4);
    float*          bsum = (float*)carve(512 * 4);

    // 1) weight transpose->bf16 + X gather->bf16 (fused, independent blocks)
    prep<<<4192, 256, 0, stream>>>(
        head_W1, tail_W1, head_W2, tail_W2, bil_W,
        W1ht, W1tt, W2ht, W2tt, bW0t, bW1t,
        hidden, ent_start, ent_label, emb, Xbf);

    // 2) layer1: Y1 = relu(X @ [W1h|W1t] + b1), N=1536 (Nh=768), K=1536
    gemm_mfma<true, true, false, true><<<dim3(24, 16), 256, 0, stream>>>(
        Xbf, 1536, 0, W1ht, W1tt, 768, head_b1, tail_b1, 1536,
        nullptr, Y1bf, 1536);

    // 3) layer2: HT = relu(Y1 @ [W2h|W2t] + b2), N=768 (Nh=384), K=768,
    //    tail half reads Y1 cols 768.. ; outputs fp32 + bf16
    gemm_mfma<true, true, true, true><<<dim3(12, 16), 256, 0, stream>>>(
        Y1bf, 1536, 768, W2ht, W2tt, 384, head_b2, tail_b2, 768,
        HT, HTbf, 768);

    // 4) bilinear left product: hW = heads @ bil_W[o], N=768 (Nh=384), K=384
    gemm_mfma<false, false, true, false><<<dim3(12, 16), 256, 0, stream>>>(
        HTbf, 768, 0, bW0t, bW1t, 384, nullptr, nullptr, 384,
        hW, nullptr, 768);

    // 5) scalar linear projections
    lin_proj<<<256, 256, 0, stream>>>(HT, lin_W, hlin, tlin);

    // 6) per-relation logits + CE partials
    rel_kernel<<<512, 256, 0, stream>>>(HT, hW, hlin, tlin, lin_b,
                                        rel_head, rel_tail, rel_label, out, bsum);

    // 7) loss reduction
    finalize<<<1, 512, 0, stream>>>(bsum, out);
}

// Round 4
// 161.396 us; speedup vs baseline: 1.7913x; 1.1649x over previous
//
#include <hip/hip_runtime.h>
#include <math.h>

// Problem constants
#define BB 2
#define LL 512
#define HH 768
#define EE 512
#define RR 32768
#define H2 384
#define MM 1024   // B*E entity rows

typedef __attribute__((ext_vector_type(8))) short     bf16x8;  // MFMA A/B frag (4 VGPRs)
typedef __attribute__((ext_vector_type(4))) float     f32x4;   // MFMA C/D frag
typedef __attribute__((ext_vector_type(8))) unsigned short u16x8;

__device__ __forceinline__ unsigned short f2bf(float f) {
    unsigned int u = __float_as_uint(f);
    u = (u + 0x7FFFu + ((u >> 16) & 1u)) >> 16;   // round-to-nearest-even
    return (unsigned short)u;
}

// ---------------------------------------------------------------------------
// prep: blocks [0,3168) transpose+convert the 6 weight matrices [K][N] fp32
// -> [N][K] bf16; blocks [3168,4192) build X bf16 (concat(hidden@start, emb)).
// ---------------------------------------------------------------------------
__global__ __launch_bounds__(256) void prep(
    const float* __restrict__ hW1, const float* __restrict__ tW1,
    const float* __restrict__ hW2, const float* __restrict__ tW2,
    const float* __restrict__ bilW,
    unsigned short* __restrict__ W1ht, unsigned short* __restrict__ W1tt,
    unsigned short* __restrict__ W2ht, unsigned short* __restrict__ W2tt,
    unsigned short* __restrict__ bW0t, unsigned short* __restrict__ bW1t,
    const float* __restrict__ hidden, const int* __restrict__ ent_start,
    const int* __restrict__ ent_label, const float* __restrict__ emb,
    unsigned short* __restrict__ Xbf)
{
    __shared__ unsigned short T[32 * 40];
    const int bid = blockIdx.x;
    const int t = threadIdx.x;

    if (bid >= 3168) {
        // ---- build X[m] = concat(hidden[b, ent_start], emb[label]) as bf16
        const int m = bid - 3168;          // 0..1023
        if (t >= 192) return;
        const int b = m >> 9;
        const int idx = ent_start[m];
        const int lab = ent_label[m];
        float4 v0, v1;
        if (t < 96) {
            const float4* s = (const float4*)(hidden + (size_t)(b * LL + idx) * HH);
            v0 = s[2 * t]; v1 = s[2 * t + 1];
        } else {
            const float4* s = (const float4*)(emb + (size_t)lab * HH);
            v0 = s[2 * t - 192]; v1 = s[2 * t - 191];
        }
        u16x8 o;
        o[0] = f2bf(v0.x); o[1] = f2bf(v0.y); o[2] = f2bf(v0.z); o[3] = f2bf(v0.w);
        o[4] = f2bf(v1.x); o[5] = f2bf(v1.y); o[6] = f2bf(v1.z); o[7] = f2bf(v1.w);
        *(u16x8*)(Xbf + (size_t)m * 1536 + 8 * t) = o;
        return;
    }

    // ---- weight transpose
    const float* src; unsigned short* dst; int K, N, tile;
    if (bid < 1152)      { src = hW1;            dst = W1ht; K = 1536; N = 768; tile = bid; }
    else if (bid < 2304) { src = tW1;            dst = W1tt; K = 1536; N = 768; tile = bid - 1152; }
    else if (bid < 2592) { src = hW2;            dst = W2ht; K = 768;  N = 384; tile = bid - 2304; }
    else if (bid < 2880) { src = tW2;            dst = W2tt; K = 768;  N = 384; tile = bid - 2592; }
    else if (bid < 3024) { src = bilW;           dst = bW0t; K = 384;  N = 384; tile = bid - 2880; }
    else                 { src = bilW + 384*384; dst = bW1t; K = 384;  N = 384; tile = bid - 3024; }
    const int tn = N >> 5;
    const int n0 = (tile % tn) * 32;
    const int k0 = (tile / tn) * 32;

    const int r  = t >> 3;           // 0..31 (k within tile)
    const int c4 = (t & 7) * 4;      // 0..28 (n within tile)
    const float4 g = *(const float4*)(src + (size_t)(k0 + r) * N + n0 + c4);
    T[(c4 + 0) * 40 + r] = f2bf(g.x);
    T[(c4 + 1) * 40 + r] = f2bf(g.y);
    T[(c4 + 2) * 40 + r] = f2bf(g.z);
    T[(c4 + 3) * 40 + r] = f2bf(g.w);
    __syncthreads();
    const int n  = t >> 3;           // 0..31
    const int k4 = (t & 7) * 4;      // 0..28
    *(ushort4*)(dst + (size_t)(n0 + n) * K + k0 + k4) = *(ushort4*)&T[n * 40 + k4];
}

// ---------------------------------------------------------------------------
// bf16 MFMA GEMM. 64x64 tile, 256 threads (4 waves, 2x2), 16x16x32 MFMA.
// A: [M][lda] bf16 row-major (k-contiguous); half 1 (n0>=Nh) uses k-offset
//    aoff1 into A and B matrix Bt1.
// B: transposed [*][ldb] bf16; row index gets +((m0>>9)*bt_mrow) for
//    batch-blocked GEMMs (bt_mrow=512) so B rows come from A's batch.
// C = act(A·B + bias): written fp32 (Cf) and/or bf16 (Cb), ldc = full N.
// LDS rows padded to 40 bf16 (80 B): staging + frag reads at bank floor.
// ---------------------------------------------------------------------------
template<bool RELU, bool BIAS, bool WF32, bool WBF16>
__global__ __launch_bounds__(256) void gemm_mfma(
    const unsigned short* __restrict__ A, int lda, int aoff1,
    const unsigned short* __restrict__ Bt0, const unsigned short* __restrict__ Bt1,
    int ldb, int bt_mrow, int Nh,
    const float* __restrict__ bias0, const float* __restrict__ bias1,
    int K, float* __restrict__ Cf, unsigned short* __restrict__ Cb, int ldc)
{
    __shared__ unsigned short As[64 * 40];
    __shared__ unsigned short Bs[64 * 40];

    const int tid = threadIdx.x;
    const int n0 = blockIdx.x * 64;
    const int m0 = blockIdx.y * 64;
    const int hf = (n0 >= Nh) ? 1 : 0;
    const unsigned short* Bt = hf ? Bt1 : Bt0;
    const int nc0 = n0 - (hf ? Nh : 0);
    const int aoff = hf ? aoff1 : 0;

    // staging: thread t covers row sr (m for A, n for B), 8 bf16 at k-offset sk
    const int sr = tid >> 2;            // 0..63
    const int sk = (tid & 3) * 8;       // 0,8,16,24

    const unsigned short* Ap = A + (size_t)(m0 + sr) * lda + aoff + sk;
    const unsigned short* Bp = Bt + (size_t)((m0 >> 9) * bt_mrow + nc0 + sr) * ldb + sk;

    const int lane = tid & 63;
    const int wave = tid >> 6;
    const int wm = (wave & 1) * 32;
    const int wn = (wave >> 1) * 32;
    const int l15 = lane & 15;
    const int quad = lane >> 4;

    f32x4 acc00 = {}, acc01 = {}, acc10 = {}, acc11 = {};

    for (int k0 = 0; k0 < K; k0 += 32) {
        const u16x8 av = *(const u16x8*)(Ap + k0);
        const u16x8 bv = *(const u16x8*)(Bp + k0);
        __syncthreads();                 // previous iter's readers done
        *(u16x8*)&As[sr * 40 + sk] = av;
        *(u16x8*)&Bs[sr * 40 + sk] = bv;
        __syncthreads();
        const bf16x8 a0 = *(const bf16x8*)&As[(wm + l15) * 40 + quad * 8];
        const bf16x8 a1 = *(const bf16x8*)&As[(wm + 16 + l15) * 40 + quad * 8];
        const bf16x8 b0 = *(const bf16x8*)&Bs[(wn + l15) * 40 + quad * 8];
        const bf16x8 b1 = *(const bf16x8*)&Bs[(wn + 16 + l15) * 40 + quad * 8];
        acc00 = __builtin_amdgcn_mfma_f32_16x16x32_bf16(a0, b0, acc00, 0, 0, 0);
        acc01 = __builtin_amdgcn_mfma_f32_16x16x32_bf16(a0, b1, acc01, 0, 0, 0);
        acc10 = __builtin_amdgcn_mfma_f32_16x16x32_bf16(a1, b0, acc10, 0, 0, 0);
        acc11 = __builtin_amdgcn_mfma_f32_16x16x32_bf16(a1, b1, acc11, 0, 0, 0);
    }

    // epilogue: C/D layout col=lane&15, row=quad*4+reg
    float bias_v0 = 0.f, bias_v1 = 0.f;
    if (BIAS) {
        const float* bb = hf ? bias1 : bias0;
        bias_v0 = bb[nc0 + wn + l15];
        bias_v1 = bb[nc0 + wn + 16 + l15];
    }
    const f32x4 accs[2][2] = {{acc00, acc01}, {acc10, acc11}};
    #pragma unroll
    for (int mi = 0; mi < 2; ++mi) {
        #pragma unroll
        for (int ni = 0; ni < 2; ++ni) {
            const int col = n0 + wn + ni * 16 + l15;
            const float bv = ni ? bias_v1 : bias_v0;
            #pragma unroll
            for (int r = 0; r < 4; ++r) {
                const int row = m0 + wm + mi * 16 + quad * 4 + r;
                float v = accs[mi][ni][r];
                if (BIAS) v += bv;
                if (RELU) v = fmaxf(v, 0.f);
                if (WF32) Cf[(size_t)row * ldc + col] = v;
                if (WBF16) Cb[(size_t)row * ldc + col] = f2bf(v);
            }
        }
    }
}

// ---------------------------------------------------------------------------
// hlin[m,o] = dot(heads[m], lin_W[0:384, o]); tlin from lin_W[384:768].
// ---------------------------------------------------------------------------
__global__ __launch_bounds__(256) void lin_proj(
    const float* __restrict__ HT, const float* __restrict__ linW,
    float* __restrict__ hlin, float* __restrict__ tlin)
{
    const int tid = threadIdx.x;
    const int lane = tid & 63;
    const int wave = tid >> 6;
    const int m = blockIdx.x * 4 + wave;
    const float* hr = HT + (size_t)m * 768;
    const float* tr = hr + 384;
    float hl0 = 0.f, hl1 = 0.f, tl0 = 0.f, tl1 = 0.f;
    #pragma unroll
    for (int t = 0; t < 6; ++t) {
        const int c = lane + 64 * t;
        const float hv = hr[c];
        const float tv = tr[c];
        const float2 wh = *(const float2*)(linW + 2 * c);
        const float2 wt = *(const float2*)(linW + 2 * (384 + c));
        hl0 += hv * wh.x; hl1 += hv * wh.y;
        tl0 += tv * wt.x; tl1 += tv * wt.y;
    }
    #pragma unroll
    for (int o = 32; o >= 1; o >>= 1) {
        hl0 += __shfl_xor(hl0, o, 64);
        hl1 += __shfl_xor(hl1, o, 64);
        tl0 += __shfl_xor(tl0, o, 64);
        tl1 += __shfl_xor(tl1, o, 64);
    }
    if (lane == 0) {
        hlin[2 * m]     = hl0;
        hlin[2 * m + 1] = hl1;
        tlin[2 * m]     = tl0;
        tlin[2 * m + 1] = tl1;
    }
}

// ---------------------------------------------------------------------------
// Per-relation gather from the E×E score table + CE partials.
// One thread per relation. Stab[mh][o*512 + t], mh = b*512 + h.
// ---------------------------------------------------------------------------
__global__ __launch_bounds__(256) void rel_gather(
    const float* __restrict__ Stab,
    const float* __restrict__ hlin, const float* __restrict__ tlin,
    const float* __restrict__ lin_b,
    const int* __restrict__ rel_head, const int* __restrict__ rel_tail,
    const int* __restrict__ rel_label,
    float* __restrict__ out, float* __restrict__ bsum)
{
    const int tid = threadIdx.x;
    const int i = blockIdx.x * 256 + tid;       // relation 0..65535
    const int b = i >> 15;
    const int h = rel_head[i];
    const int t = rel_tail[i];
    const int lab = rel_label[i];
    const int mh = (b << 9) + h;
    const int mt = (b << 9) + t;

    const float2 hl = ((const float2*)hlin)[mh];
    const float2 tl = ((const float2*)tlin)[mt];
    const float* srow = Stab + (size_t)mh * 1024;
    const float z0 = srow[t]       + hl.x + tl.x + lin_b[0];
    const float z1 = srow[512 + t] + hl.y + tl.y + lin_b[1];
    out[1 + 2 * (size_t)i]     = z0;
    out[2 + 2 * (size_t)i]     = z1;

    const float mx = fmaxf(z0, z1);
    const float mn = fminf(z0, z1);
    const float lse = mx + log1pf(expf(mn - mx));
    float ce = lse - (lab ? z1 : z0);

    // block reduce (4 waves)
    #pragma unroll
    for (int o = 32; o >= 1; o >>= 1) ce += __shfl_xor(ce, o, 64);
    __shared__ float wsum[4];
    if ((tid & 63) == 0) wsum[tid >> 6] = ce;
    __syncthreads();
    if (tid == 0) bsum[blockIdx.x] = wsum[0] + wsum[1] + wsum[2] + wsum[3];
}

__global__ __launch_bounds__(256) void finalize(
    const float* __restrict__ bsum, float* __restrict__ out)
{
    const int tid = threadIdx.x;
    float v = bsum[tid];
    #pragma unroll
    for (int o = 32; o >= 1; o >>= 1) v += __shfl_xor(v, o, 64);
    __shared__ float s[4];
    if ((tid & 63) == 0) s[tid >> 6] = v;
    __syncthreads();
    if (tid == 0) {
        out[0] = (s[0] + s[1] + s[2] + s[3]) * (1.0f / (float)RR);
    }
}

// ---------------------------------------------------------------------------
extern "C" void kernel_launch(void* const* d_in, const int* in_sizes, int n_in,
                              void* d_out, int out_size, void* d_ws, size_t ws_size,
                              hipStream_t stream) {
    const float* hidden    = (const float*)d_in[0];
    const int*   ent_start = (const int*)d_in[1];
    const int*   ent_label = (const int*)d_in[2];
    const int*   rel_head  = (const int*)d_in[3];
    const int*   rel_tail  = (const int*)d_in[4];
    const int*   rel_label = (const int*)d_in[5];
    const float* emb       = (const float*)d_in[6];
    const float* head_W1   = (const float*)d_in[7];
    const float* head_b1   = (const float*)d_in[8];
    const float* head_W2   = (const float*)d_in[9];
    const float* head_b2   = (const float*)d_in[10];
    const float* tail_W1   = (const float*)d_in[11];
    const float* tail_b1   = (const float*)d_in[12];
    const float* tail_W2   = (const float*)d_in[13];
    const float* tail_b2   = (const float*)d_in[14];
    const float* bil_W     = (const float*)d_in[15];
    const float* lin_W     = (const float*)d_in[16];
    const float* lin_b     = (const float*)d_in[17];
    float* out = (float*)d_out;

    // Workspace carve-up (256B-aligned chunks)
    char* w = (char*)d_ws;
    auto carve = [&](size_t bytes) {
        char* p = w; w += (bytes + 255) & ~(size_t)255; return p;
    };
    unsigned short* Xbf  = (unsigned short*)carve((size_t)MM * 1536 * 2);
    unsigned short* Y1bf = (unsigned short*)carve((size_t)MM * 1536 * 2);
    unsigned short* HTbf = (unsigned short*)carve((size_t)MM * 768 * 2);
    float*          HT   = (float*)carve((size_t)MM * 768 * 4);
    unsigned short* hWbf = (unsigned short*)carve((size_t)MM * 768 * 2);
    float*          Stab = (float*)carve((size_t)MM * 1024 * 4);
    unsigned short* W1ht = (unsigned short*)carve((size_t)768 * 1536 * 2);
    unsigned short* W1tt = (unsigned short*)carve((size_t)768 * 1536 * 2);
    unsigned short* W2ht = (unsigned short*)carve((size_t)384 * 768 * 2);
    unsigned short* W2tt = (unsigned short*)carve((size_t)384 * 768 * 2);
    unsigned short* bW0t = (unsigned short*)carve((size_t)384 * 384 * 2);
    unsigned short* bW1t = (unsigned short*)carve((size_t)384 * 384 * 2);
    float*          hlin = (float*)carve(2048 * 4);
    float*          tlin = (float*)carve(2048 * 4);
    float*          bsum = (float*)carve(256 * 4);

    // 1) weight transpose->bf16 + X gather->bf16 (fused, independent blocks)
    prep<<<4192, 256, 0, stream>>>(
        head_W1, tail_W1, head_W2, tail_W2, bil_W,
        W1ht, W1tt, W2ht, W2tt, bW0t, bW1t,
        hidden, ent_start, ent_label, emb, Xbf);

    // 2) layer1: Y1 = relu(X @ [W1h|W1t] + b1), N=1536 (Nh=768), K=1536
    gemm_mfma<true, true, false, true><<<dim3(24, 16), 256, 0, stream>>>(
        Xbf, 1536, 0, W1ht, W1tt, 1536, 0, 768, head_b1, tail_b1, 1536,
        nullptr, Y1bf, 1536);

    // 3) layer2: HT = relu(Y1 @ [W2h|W2t] + b2), N=768 (Nh=384), K=768,
    //    tail half reads Y1 cols 768.. ; outputs fp32 + bf16
    gemm_mfma<true, true, true, true><<<dim3(12, 16), 256, 0, stream>>>(
        Y1bf, 1536, 768, W2ht, W2tt, 768, 0, 384, head_b2, tail_b2, 768,
        HT, HTbf, 768);

    // 4) bilinear left product: hWbf = heads @ bil_W[o], N=768 (Nh=384), K=384
    gemm_mfma<false, false, false, true><<<dim3(12, 16), 256, 0, stream>>>(
        HTbf, 768, 0, bW0t, bW1t, 384, 0, 384, nullptr, nullptr, 384,
        nullptr, hWbf, 768);

    // 5) score table: Stab[mh][o*512+t] = hWbf[mh, o*384:..] . tails[b,t,:]
    //    A = hWbf (lda=768, aoff1=384 selects o=1), B = HTbf tails cols
    //    (ldb=768, +384 col offset), batch-blocked rows via bt_mrow=512.
    gemm_mfma<false, false, true, false><<<dim3(16, 16), 256, 0, stream>>>(
        hWbf, 768, 384, HTbf + 384, HTbf + 384, 768, 512, 512,
        nullptr, nullptr, 384, Stab, nullptr, 1024);

    // 6) scalar linear projections
    lin_proj<<<256, 256, 0, stream>>>(HT, lin_W, hlin, tlin);

    // 7) per-relation gather + CE partials
    rel_gather<<<256, 256, 0, stream>>>(Stab, hlin, tlin, lin_b,
                                        rel_head, rel_tail, rel_label, out, bsum);

    // 8) loss reduction
    finalize<<<1, 256, 0, stream>>>(bsum, out);
}